// Round 2
// baseline (84.022 us; speedup 1.0000x reference)
//
#include <hip/hip_runtime.h>
#include <math.h>

// Tiny_ConvCIFAR10_KAN_Discriminator — per-PIXEL formulation.
//
// out[b] = sigmoid( (1/256) * [ corr + sum_{real pixels p} Q_{c,rc(r),cc(col)}(v_p) ] + lb )
//
// Derivation: after folding lin_w into the weights, the result is a plain sum of
// P_f(v) over all (position, feature) pairs, where P_f is piecewise-quadratic in v
// (quadratic B-spline on uniform knots, half-interval index i2 = floor(3v+7)+1
// clamped to [0,15]; ReLU*base folded into the beta coefficient for x>=0 rows,
// top clamp row = bwc*x exactly, bottom clamp row = 0). A pixel at (r,col)
// occurs at a class-determined set of (kh,kw) offsets (row class: r==0 ->{1},
// even interior ->{1,3}, odd interior ->{0,2}, r==31 ->{2}; same for columns),
// and the sum of those quadratics is one quadratic -> one table row per pixel.
// Zero-pad pixels contribute a per-image constant corr = sum_f N_f * alpha_{f,row8}.

__global__ __launch_bounds__(256) void kan_pixel(
    const float* __restrict__ x,    // [B][3][32][32]
    const float* __restrict__ bw,   // [8][48]
    const float* __restrict__ sw,   // [8][48][5]
    const float* __restrict__ lw,   // [8]
    const float* __restrict__ lb,   // [1]
    float* __restrict__ out)        // [B]
{
  __shared__ float  Spad[480];   // [f][10]: folded spline wts, S[k] at m=k+2, zero-padded
  __shared__ float  bwcL[48];    // folded base wts
  __shared__ float4 P[768];      // [f][16]  (alpha, beta, gamma, 0)
  __shared__ float4 T[768];      // [(c*4+rc)*4+ccl][16] class-summed polynomials
  __shared__ float  red[4];
  __shared__ float  corrS;

  const int tid = threadIdx.x;
  const int b = blockIdx.x;

  // ---- issue this thread's 12 pixels early (coalesced float4); build hides latency ----
  const float4* xg = reinterpret_cast<const float4*>(x) + (size_t)b * 768;
  float4 px0 = xg[tid];
  float4 px1 = xg[tid + 256];
  float4 px2 = xg[tid + 512];

  float l[8];
  #pragma unroll
  for (int o = 0; o < 8; ++o) l[o] = lw[o];

  // ---- stage 0: fold lin_w into spline/base weights (L2-hot, redundant per block) ----
  for (int e = tid; e < 480; e += 256) {
    int f = e / 10, m = e - f * 10;
    float v = 0.f;
    if (m >= 2 && m < 7) {
      int k = f * 5 + (m - 2);
      #pragma unroll
      for (int o = 0; o < 8; ++o) v = fmaf(l[o], sw[o * 240 + k], v);
    }
    Spad[e] = v;
  }
  if (tid < 48) {
    float v = 0.f;
    #pragma unroll
    for (int o = 0; o < 8; ++o) v = fmaf(l[o], bw[o * 48 + tid], v);
    bwcL[tid] = v;
  }
  __syncthreads();

  // ---- stage 1: per-feature piecewise quadratic P_f[i2] = (alpha,beta,gamma) ----
  #pragma unroll
  for (int k = 0; k < 3; ++k) {
    int e = tid + k * 256;
    int f = e >> 4, i2 = e & 15;
    float4 r4 = make_float4(0.f, 0.f, 0.f, 0.f);
    if (i2 != 0) {                      // i2==0: all x < -7/3 -> zero polynomial
      int j2 = i2 - 1, j = j2 >> 1;     // knot interval j, half-interval j2
      float d = 3.5f - (float)j;        // t = 1.5x + d on this interval
      float s0 = Spad[f * 10 + j];      // S[j-2] (zero-padded)
      float s1 = Spad[f * 10 + j + 1];  // S[j-1]
      float s2 = Spad[f * 10 + j + 2];  // S[j]
      float A = 0.5f * (s0 + s1);       // t-poly: A + B t + C t^2
      float B = s1 - s0;
      float C = 0.5f * s0 - s1 + 0.5f * s2;
      r4.x = A + d * (B + d * C);                                 // alpha
      r4.y = 1.5f * B + 3.f * d * C + (j2 >= 7 ? bwcL[f] : 0.f);  // beta (+ReLU fold, x>=0)
      r4.z = 2.25f * C;                                           // gamma
    }
    P[e] = r4;
  }
  __syncthreads();

  // ---- pad-pixel correction: N_f occurrences of P_f(0) = alpha at row 8 ----
  if (tid == 0) {
    float cs = 0.f;
    for (int f = 0; f < 48; ++f) {
      int kh = (f >> 2) & 3, kw = f & 3;
      int eh = (kh == 0 || kh == 3) ? 1 : 0;
      int ew = (kw == 0 || kw == 3) ? 1 : 0;
      float n = (float)(16 * eh + 16 * ew - (eh & ew));
      cs = fmaf(n, P[f * 16 + 8].x, cs);
    }
    corrS = cs;
  }

  // ---- stage 2: class-summed table T; row classes {1,3},{1},{0,2},{2} (cols same) ----
  #pragma unroll
  for (int k = 0; k < 3; ++k) {
    int e = tid + k * 256;
    int i2 = e & 15, g = e >> 4;
    int ccl = g & 3, rc = (g >> 2) & 3, c = g >> 4;
    int khA = (0x2011 >> (rc * 4)) & 15;   // {rc0:1, rc1:1, rc2:0, rc3:2}
    int kwA = (0x2011 >> (ccl * 4)) & 15;
    bool hB = !(rc & 1);                   // second kh (=khA+2) valid
    bool wB = !(ccl & 1);                  // second kw (=kwA+2) valid
    int fAA = ((c * 4 + khA) * 4 + kwA) * 16 + i2;
    float4 a = P[fAA];
    if (wB)       { float4 p = P[fAA + 32];  a.x += p.x; a.y += p.y; a.z += p.z; }
    if (hB)       { float4 p = P[fAA + 128]; a.x += p.x; a.y += p.y; a.z += p.z; }
    if (hB && wB) { float4 p = P[fAA + 160]; a.x += p.x; a.y += p.y; a.z += p.z; }
    T[e] = a;
  }
  __syncthreads();

  // ---- main: 12 pixels, one table row each ----
  float s = 0.f;
  auto acc1 = [&](float v, int fb) {
    float fj = floorf(fmaf(v, 3.f, 7.f));        // half-interval j2
    fj = fminf(fmaxf(fj, -1.f), 14.f);           // clamp rows handle all tails exactly
    int i2 = (int)fj + 1;
    float4 co = T[fb + i2];
    s = fmaf(v, fmaf(v, co.z, co.y), s + co.x);
  };
  const float4 pxa[3] = {px0, px1, px2};
  #pragma unroll
  for (int i = 0; i < 3; ++i) {
    int i4 = tid + (i << 8);
    int flat = i4 << 2;
    int c = flat >> 10;
    int rem = flat & 1023;
    int r = rem >> 5;
    int col0 = rem & 31;                          // multiple of 4
    int rc = ((r & 1) << 1) + (r == 0 ? 1 : 0) + (r == 31 ? 1 : 0);
    int base = (((c << 2) | rc) << 6);            // ((c*4+rc)*4)*16 float4 rows
    acc1(pxa[i].x, base + ((col0 == 0) ? 16 : 0));   // col even: ccl 0/1
    acc1(pxa[i].y, base + 32);                        // col odd interior: ccl 2
    acc1(pxa[i].z, base);                             // col even interior: ccl 0
    acc1(pxa[i].w, base + ((col0 == 28) ? 48 : 32));  // col odd / col==31: ccl 2/3
  }

  // ---- block reduce (4 waves), mean incl. pad correction, sigmoid ----
  #pragma unroll
  for (int off = 32; off; off >>= 1) s += __shfl_down(s, off);
  if ((tid & 63) == 0) red[tid >> 6] = s;
  __syncthreads();
  if (tid == 0) {
    float tot = (red[0] + red[1]) + (red[2] + red[3]) + corrS;
    float z = tot * (1.f / 256.f) + lb[0];
    out[b] = 1.f / (1.f + expf(-z));
  }
}

extern "C" void kernel_launch(void* const* d_in, const int* in_sizes, int n_in,
                              void* d_out, int out_size, void* d_ws, size_t ws_size,
                              hipStream_t stream) {
  const float* x  = (const float*)d_in[0];
  const float* bw = (const float*)d_in[1];
  const float* sw = (const float*)d_in[2];
  const float* lw = (const float*)d_in[3];
  const float* lb = (const float*)d_in[4];
  float* out = (float*)d_out;
  int B = in_sizes[0] / 3072;   // 2048
  kan_pixel<<<B, 256, 0, stream>>>(x, bw, sw, lw, lb, out);
}

// Round 3
// 79.469 us; speedup vs baseline: 1.0573x; 1.0573x over previous
//
#include <hip/hip_runtime.h>
#include <math.h>

// Tiny_ConvCIFAR10_KAN_Discriminator — per-PIXEL formulation, split into
// (1) a one-block table builder writing d_ws, (2) a lean 2048-block main kernel.
//
// out[b] = sigmoid( (1/256) * [ corr + sum_{real pixels p} Q_{c,rc(r),cc(col)}(v_p) ] + lb )
//
// After folding lin_w into the weights, the result is a plain sum of P_f(v) over
// all (position, feature) pairs, where P_f is piecewise-quadratic in v (quadratic
// B-spline on uniform knots; half-interval index i2 = floor(3v+7)+1 clamped to
// [0,15]; ReLU*base folded into beta for x>=0 rows; top clamp row = bwc*x exactly,
// bottom clamp row = 0). A pixel at (r,col) occurs at a class-determined set of
// (kh,kw) offsets (row class: r==0 ->{1}, even interior ->{1,3}, odd interior
// ->{0,2}, r==31 ->{2}; columns identical), and the sum of those quadratics is one
// quadratic -> one float4 table row per pixel. Zero-pad pixels contribute a
// per-image constant corr = sum_f N_f * alpha_{f,row8}.
//
// d_ws layout: float4 T[768] (12288 B) + float corr at ((float*)d_ws)[3072].

__global__ __launch_bounds__(256) void kan_build(
    const float* __restrict__ bw,   // [8][48]
    const float* __restrict__ sw,   // [8][48][5]
    const float* __restrict__ lw,   // [8]
    float* __restrict__ ws)         // d_ws
{
  __shared__ float  Spad[480];   // [f][10]: folded spline wts, S[k] at m=k+2, zero-pad
  __shared__ float  bwcL[48];
  __shared__ float4 P[768];      // [f][16] (alpha, beta, gamma, 0)
  __shared__ float  c48[48];

  const int tid = threadIdx.x;
  float l[8];
  #pragma unroll
  for (int o = 0; o < 8; ++o) l[o] = lw[o];

  // stage 0: fold lin_w into spline/base weights
  for (int e = tid; e < 480; e += 256) {
    int f = e / 10, m = e - f * 10;
    float v = 0.f;
    if (m >= 2 && m < 7) {
      int k = f * 5 + (m - 2);
      #pragma unroll
      for (int o = 0; o < 8; ++o) v = fmaf(l[o], sw[o * 240 + k], v);
    }
    Spad[e] = v;
  }
  if (tid < 48) {
    float v = 0.f;
    #pragma unroll
    for (int o = 0; o < 8; ++o) v = fmaf(l[o], bw[o * 48 + tid], v);
    bwcL[tid] = v;
  }
  __syncthreads();

  // stage 1: per-feature piecewise quadratic P_f[i2] = (alpha,beta,gamma)
  #pragma unroll
  for (int k = 0; k < 3; ++k) {
    int e = tid + k * 256;
    int f = e >> 4, i2 = e & 15;
    float4 r4 = make_float4(0.f, 0.f, 0.f, 0.f);
    if (i2 != 0) {                      // i2==0: all x < -7/3 -> zero polynomial
      int j2 = i2 - 1, j = j2 >> 1;     // knot interval j, half-interval j2
      float d = 3.5f - (float)j;        // t = 1.5x + d on this interval
      float s0 = Spad[f * 10 + j];      // S[j-2]
      float s1 = Spad[f * 10 + j + 1];  // S[j-1]
      float s2 = Spad[f * 10 + j + 2];  // S[j]
      float A = 0.5f * (s0 + s1);       // t-poly: A + B t + C t^2
      float B = s1 - s0;
      float C = 0.5f * s0 - s1 + 0.5f * s2;
      r4.x = A + d * (B + d * C);                                 // alpha
      r4.y = 1.5f * B + 3.f * d * C + (j2 >= 7 ? bwcL[f] : 0.f);  // beta (+ReLU fold)
      r4.z = 2.25f * C;                                           // gamma
    }
    P[e] = r4;
  }
  __syncthreads();

  // pad-pixel correction terms: N_f occurrences of P_f(0) = alpha at row 8
  if (tid < 48) {
    int kh = (tid >> 2) & 3, kw = tid & 3;
    int eh = (kh == 0 || kh == 3) ? 1 : 0;
    int ew = (kw == 0 || kw == 3) ? 1 : 0;
    float n = (float)(16 * eh + 16 * ew - (eh & ew));
    c48[tid] = n * P[tid * 16 + 8].x;
  }

  // stage 2: class-summed table T -> global; classes {1,3},{1},{0,2},{2}
  float4* tg = reinterpret_cast<float4*>(ws);
  #pragma unroll
  for (int k = 0; k < 3; ++k) {
    int e = tid + k * 256;
    int i2 = e & 15, g = e >> 4;
    int ccl = g & 3, rc = (g >> 2) & 3, c = g >> 4;
    int khA = (0x2011 >> (rc * 4)) & 15;   // {rc0:1, rc1:1, rc2:0, rc3:2}
    int kwA = (0x2011 >> (ccl * 4)) & 15;
    bool hB = !(rc & 1);                   // second kh (=khA+2) valid
    bool wB = !(ccl & 1);                  // second kw (=kwA+2) valid
    int fAA = ((c * 4 + khA) * 4 + kwA) * 16 + i2;
    float4 a = P[fAA];
    if (wB)       { float4 p = P[fAA + 32];  a.x += p.x; a.y += p.y; a.z += p.z; }
    if (hB)       { float4 p = P[fAA + 128]; a.x += p.x; a.y += p.y; a.z += p.z; }
    if (hB && wB) { float4 p = P[fAA + 160]; a.x += p.x; a.y += p.y; a.z += p.z; }
    tg[e] = a;
  }
  __syncthreads();
  if (tid == 0) {
    float cs = 0.f;
    for (int f = 0; f < 48; ++f) cs += c48[f];   // same order as reference loop
    ws[3072] = cs;
  }
}

__global__ __launch_bounds__(256) void kan_main(
    const float* __restrict__ x,    // [B][3][32][32]
    const float* __restrict__ ws,   // table + corr
    const float* __restrict__ lb,   // [1]
    float* __restrict__ out)        // [B]
{
  __shared__ float4 T[768];
  __shared__ float  red[4];

  const int tid = threadIdx.x;
  const int b = blockIdx.x;

  // image loads first (in flight across the staging barrier)
  const float4* xg = reinterpret_cast<const float4*>(x) + (size_t)b * 768;
  float4 px0 = xg[tid];
  float4 px1 = xg[tid + 256];
  float4 px2 = xg[tid + 512];

  // stage the 12 KB table from L2
  const float4* tg = reinterpret_cast<const float4*>(ws);
  T[tid]       = tg[tid];
  T[tid + 256] = tg[tid + 256];
  T[tid + 512] = tg[tid + 512];
  __syncthreads();

  float s = 0.f;
  auto acc1 = [&](float v, int fb) {
    float fj = floorf(fmaf(v, 3.f, 7.f));        // half-interval j2
    fj = fminf(fmaxf(fj, -1.f), 14.f);           // clamp rows handle tails exactly
    int i2 = (int)fj + 1;
    float4 co = T[fb + i2];
    s = fmaf(v, fmaf(v, co.z, co.y), s + co.x);
  };
  const float4 pxa[3] = {px0, px1, px2};
  #pragma unroll
  for (int i = 0; i < 3; ++i) {
    int i4 = tid + (i << 8);
    int flat = i4 << 2;
    int c = flat >> 10;
    int rem = flat & 1023;
    int r = rem >> 5;
    int col0 = rem & 31;                          // multiple of 4
    int rc = ((r & 1) << 1) + (r == 0 ? 1 : 0) + (r == 31 ? 1 : 0);
    int base = (((c << 2) | rc) << 6);            // ((c*4+rc)*4)*16 float4 rows
    acc1(pxa[i].x, base + ((col0 == 0) ? 16 : 0));   // col even: ccl 0/1
    acc1(pxa[i].y, base + 32);                        // col odd interior: ccl 2
    acc1(pxa[i].z, base);                             // col even interior: ccl 0
    acc1(pxa[i].w, base + ((col0 == 28) ? 48 : 32));  // col odd / col==31: ccl 2/3
  }

  #pragma unroll
  for (int off = 32; off; off >>= 1) s += __shfl_down(s, off);
  if ((tid & 63) == 0) red[tid >> 6] = s;
  __syncthreads();
  if (tid == 0) {
    float tot = (red[0] + red[1]) + (red[2] + red[3]) + ws[3072];
    float z = tot * (1.f / 256.f) + lb[0];
    out[b] = 1.f / (1.f + expf(-z));
  }
}

extern "C" void kernel_launch(void* const* d_in, const int* in_sizes, int n_in,
                              void* d_out, int out_size, void* d_ws, size_t ws_size,
                              hipStream_t stream) {
  const float* x  = (const float*)d_in[0];
  const float* bw = (const float*)d_in[1];
  const float* sw = (const float*)d_in[2];
  const float* lw = (const float*)d_in[3];
  const float* lb = (const float*)d_in[4];
  float* out = (float*)d_out;
  float* ws  = (float*)d_ws;
  int B = in_sizes[0] / 3072;   // 2048
  kan_build<<<1, 256, 0, stream>>>(bw, sw, lw, ws);
  kan_main<<<B, 256, 0, stream>>>(x, ws, lb, out);
}